// Round 1
// baseline (229.667 us; speedup 1.0000x reference)
//
#include <hip/hip_runtime.h>

#define BATCH 8192
#define IN_F 4096
#define OUT_F 4096

__global__ __launch_bounds__(256) void
Rank1Linear_kernel(const float* __restrict__ x,
                   const float* __restrict__ w,
                   float* __restrict__ out) {
    const int row = blockIdx.x;
    const int tid = threadIdx.x;

    // ---- 1) row sum: 4096 floats = 1024 float4, 256 threads x 4 iters ----
    const float4* x4 = reinterpret_cast<const float4*>(x + (size_t)row * IN_F);
    float s = 0.f;
#pragma unroll
    for (int j = 0; j < 4; ++j) {
        float4 v = x4[j * 256 + tid];
        s += (v.x + v.y) + (v.z + v.w);
    }

    // ---- 2) wave-64 shuffle reduce, then cross-wave via LDS ----
#pragma unroll
    for (int off = 32; off > 0; off >>= 1)
        s += __shfl_down(s, off, 64);

    __shared__ float wave_sums[4];
    __shared__ float rowsum_sh;
    if ((tid & 63) == 0) wave_sums[tid >> 6] = s;
    __syncthreads();
    if (tid == 0)
        rowsum_sh = (wave_sums[0] + wave_sums[1]) + (wave_sums[2] + wave_sums[3]);
    __syncthreads();
    const float rs = rowsum_sh;

    // ---- 3) outer product row: out[row, :] = rs * w[:], coalesced float4 ----
    const float4* w4 = reinterpret_cast<const float4*>(w);
    float4* o4 = reinterpret_cast<float4*>(out + (size_t)row * OUT_F);
#pragma unroll
    for (int j = 0; j < 4; ++j) {
        float4 wv = w4[j * 256 + tid];
        float4 ov;
        ov.x = rs * wv.x;
        ov.y = rs * wv.y;
        ov.z = rs * wv.z;
        ov.w = rs * wv.w;
        o4[j * 256 + tid] = ov;
    }
}

extern "C" void kernel_launch(void* const* d_in, const int* in_sizes, int n_in,
                              void* d_out, int out_size, void* d_ws, size_t ws_size,
                              hipStream_t stream) {
    const float* x = (const float*)d_in[0];   // [8192, 4096] fp32
    const float* w = (const float*)d_in[1];   // [1, 4096] fp32
    float* out = (float*)d_out;               // [8192, 4096] fp32
    Rank1Linear_kernel<<<BATCH, 256, 0, stream>>>(x, w, out);
}